// Round 2
// baseline (1306.098 us; speedup 1.0000x reference)
//
#include <hip/hip_runtime.h>

#define A_DIM 64
#define B_DIM 128
#define E 128
#define NG 50
#define NROW (A_DIM*A_DIM*B_DIM)   // 524288
#define TR 64                      // rows per block
#define KS 136                     // xa row stride (shorts): 16B-aligned rows
#define SMS 72                     // smb row stride (shorts)
#define WBLK 512                   // shorts per (grp,plane,ksub) W fragment block (1 KB)
#define BR_STRIDE 147456           // shorts per branch: 18 chunks x 16 blocks x 512
#define NOUT (B_DIM + A_DIM*B_DIM*3)   // 24704 output floats
#define WLSCALE 64.0f              // W-lo pre-scale (avoids fp16 subnormal flush)
#define WLINV   0.015625f          // 1/64

using half8   = _Float16 __attribute__((ext_vector_type(8)));
using short8v = short __attribute__((ext_vector_type(8)));
using f32x16  = float __attribute__((ext_vector_type(16)));

__device__ __forceinline__ float silu_f(float x) {
  return x * __builtin_amdgcn_rcpf(1.0f + __expf(-x));
}
__device__ __forceinline__ short hbits(_Float16 h) {
  return (short)__builtin_bit_cast(unsigned short, h);
}

// One K=32 chunk, 2-term fp16: acc += xh*Wh ; accl += xh*(Wl*64).
// A (64 rows, single fp16 plane) from LDS; B from lane-ordered global fragment
// blocks (wl includes branch base + wave col-group + lane*8).
__device__ __forceinline__ void gemm_chunk32(
    const short* __restrict__ xh_, int xstr, int kcol,
    const short* __restrict__ wl_, int cidx,
    f32x16 acc[2], f32x16 accl[2], int l31, int l5)
{
  half8 bh[2], bl[2];
  #pragma unroll
  for (int s = 0; s < 2; ++s) {
    bh[s] = __builtin_bit_cast(half8,
              *(const short8v*)(wl_ + (size_t)(cidx * 16 + s) * WBLK));
    bl[s] = __builtin_bit_cast(half8,
              *(const short8v*)(wl_ + (size_t)(cidx * 16 + 2 + s) * WBLK));
  }
  #pragma unroll
  for (int rt = 0; rt < 2; ++rt) {
    const short* arow = xh_ + (rt * 32 + l31) * xstr + kcol + l5 * 8;
    #pragma unroll
    for (int s = 0; s < 2; ++s) {
      half8 a = __builtin_bit_cast(half8, *(const short8v*)(arow + s * 16));
      acc[rt]  = __builtin_amdgcn_mfma_f32_32x32x16_f16(a, bh[s], acc[rt],  0, 0, 0);
      accl[rt] = __builtin_amdgcn_mfma_f32_32x32x16_f16(a, bl[s], accl[rt], 0, 0, 0);
    }
  }
}

// Transpose + fp16 hi / scaled-lo split of all weights into lane-ordered
// fragment blocks. Fast axis is n -> coalesced W[k*128+n] loads.
// blk = cidx*16 + (n>>5)*4 + p*2 + (kk>>4); lane = (n&31)+32*((kk>>3)&1); e = kk&7.
__global__ __launch_bounds__(256) void prep_weights(
    const float* __restrict__ eWin, const float* __restrict__ eWh,
    const float* __restrict__ eWout, const float* __restrict__ erbf,
    const float* __restrict__ fWin, const float* __restrict__ fWh,
    const float* __restrict__ fWout, const float* __restrict__ frbf,
    short* __restrict__ S)
{
  int o = blockIdx.x * 256 + threadIdx.x;
  if (o >= 2 * 73728) return;
  int br = (o >= 73728) ? 1 : 0;
  int r = o - br * 73728;
  short* base = S + br * BR_STRIDE;
  float v; int cidx, n, kk;
  if (r < 65536) {
    int lay = r >> 14, idx = r & 16383;
    int k = idx >> 7; n = idx & 127;
    const float* W = (lay == 0) ? (br ? fWin : eWin)
                   : (lay == 3) ? (br ? fWout : eWout)
                   : ((br ? fWh : eWh) + (lay - 1) * 16384);
    v = W[k * 128 + n];
    cidx = lay * 4 + (k >> 5); kk = k & 31;
  } else {
    int rr = r - 65536;                 // 0..8191
    int k = rr >> 7; n = rr & 127;
    v = (k < NG) ? (br ? frbf : erbf)[k * 128 + n] : 0.0f;
    cidx = 16 + (k >> 5); kk = k & 31;
  }
  int blk = cidx * 16 + (n >> 5) * 4 + (kk >> 4);                    // p = 0
  int idx2 = blk * WBLK + ((n & 31) + 32 * ((kk >> 3) & 1)) * 8 + (kk & 7);
  _Float16 wh = (_Float16)v;
  _Float16 wl = (_Float16)((v - (float)wh) * WLSCALE);
  base[idx2] = hbits(wh);
  base[idx2 + 2 * WBLK] = hbits(wl);                                 // p = 1
}

__global__ __launch_bounds__(256) void zero_out(float* __restrict__ out) {
  int i = blockIdx.x * 256 + threadIdx.x;
  if (i < NOUT) out[i] = 0.0f;
}

__global__ __launch_bounds__(256, 4) void fused_main(
    const float* __restrict__ T, const float* __restrict__ mask,
    const float* __restrict__ dist, const float* __restrict__ vh,
    const float* __restrict__ ebin, const float* __restrict__ ebh,
    const float* __restrict__ ebout, const float* __restrict__ ehead,
    const float* __restrict__ fbin, const float* __restrict__ fbh,
    const float* __restrict__ fbout, const float* __restrict__ fhead,
    const short* __restrict__ S,
    float* __restrict__ out)
{
  __shared__ short xa[TR * KS];       // single fp16 plane: 17408 B
  __shared__ float part[4][TR];       // 1024 B -> 18432 B total

  const int t = threadIdx.x;
  const int wave = t >> 6, lane = t & 63;
  const int l31 = lane & 31, l5 = lane >> 5;
  const int br = blockIdx.x & 1;
  const long tile = blockIdx.x >> 1;
  const long r0g = tile * TR;

  const short* wl = S + br * BR_STRIDE + wave * (4 * WBLK) + lane * 8;
  const float* bin  = br ? fbin : ebin;
  const float* bh_  = br ? fbh : ebh;
  const float* bout = br ? fbout : ebout;
  const float* head = br ? fhead : ehead;

  // ---- T tile -> xa fp16 plane ----
  {
    int row = t >> 2, seg = t & 3;
    const float* Tp = T + (r0g + row) * E + seg * 32;
    short* ph = xa + row * KS + seg * 32;
    #pragma unroll
    for (int j = 0; j < 8; ++j) {
      float4 v = *(const float4*)(Tp + j * 4);
      short4 s4 = make_short4(hbits((_Float16)v.x), hbits((_Float16)v.y),
                              hbits((_Float16)v.z), hbits((_Float16)v.w));
      *(short4*)(ph + j * 4) = s4;
    }
  }

  f32x16 acc[2], accl[2];

  // ---- 4 dense layers; W fragments stream L2->VGPR ----
  #pragma unroll 1
  for (int lay = 0; lay < 4; ++lay) {
    const float* bg = (lay == 0) ? bin : (lay == 3) ? bout : (bh_ + (lay - 1) * E);
    float b0 = bg[wave * 32 + l31];
    #pragma unroll
    for (int i = 0; i < 16; ++i) {
      acc[0][i] = b0; acc[1][i] = b0;
      accl[0][i] = 0.f; accl[1][i] = 0.f;
    }
    __syncthreads();                   // xa writes (stage / prev epilogue) visible
    #pragma unroll
    for (int ch = 0; ch < 4; ++ch)
      gemm_chunk32(xa, KS, ch * 32, wl, lay * 4 + ch, acc, accl, l31, l5);
    __syncthreads();                   // all xa reads of this layer done
    if (lay < 3) {
      #pragma unroll
      for (int rt = 0; rt < 2; ++rt)
        #pragma unroll
        for (int rg = 0; rg < 16; ++rg) {
          float y = acc[rt][rg] + accl[rt][rg] * WLINV;
          float v = silu_f(y);
          int rowa = rt * 32 + 4 * l5 + (rg & 3) + 8 * (rg >> 2);
          int col = wave * 32 + l31;
          short* slot = xa + rowa * KS + col;
          if (lay > 0) v += (float)*(const _Float16*)slot;  // residual (own slot)
          *slot = hbits((_Float16)v);
        }
    }
  }
  // fold feat: acc = Wout output (bias included, no activation)
  #pragma unroll
  for (int rt = 0; rt < 2; ++rt)
    #pragma unroll
    for (int i = 0; i < 16; ++i) acc[rt][i] += accl[rt][i] * WLINV;

  // ---- smeared gaussians -> sm fp16 plane (overlays xa; post-loop sync covers) ----
  short* smhi = xa;
  const float stepv = 12.0f / 49.0f;
  const float coeff = -0.5f / (stepv * stepv);
  {
    int r = t & 63, kg = t >> 6;
    float d = dist[r0g + r];
    #pragma unroll
    for (int j4 = 0; j4 < 4; ++j4) {
      float vv[4];
      #pragma unroll
      for (int jj = 0; jj < 4; ++jj) {
        int k = kg * 16 + j4 * 4 + jj;
        float dd = d - (float)k * stepv;
        vv[jj] = (k < NG) ? __expf(coeff * dd * dd) : 0.0f;
      }
      short4 s4 = make_short4(hbits((_Float16)vv[0]), hbits((_Float16)vv[1]),
                              hbits((_Float16)vv[2]), hbits((_Float16)vv[3]));
      *(short4*)(smhi + r * SMS + kg * 16 + j4 * 4) = s4;
    }
  }
  float h0 = head[wave * 32 + l31];
  f32x16 acc2[2], acc2l[2];
  #pragma unroll
  for (int i = 0; i < 16; ++i) {
    acc2[0][i] = 0.f; acc2[1][i] = 0.f;
    acc2l[0][i] = 0.f; acc2l[1][i] = 0.f;
  }
  __syncthreads();                     // sm plane visible
  gemm_chunk32(smhi, SMS, 0,  wl, 16, acc2, acc2l, l31, l5);
  gemm_chunk32(smhi, SMS, 32, wl, 17, acc2, acc2l, l31, l5);

  // ---- head dot: reduce over 32 cols per wave, cross-wave via LDS ----
  #pragma unroll
  for (int rt = 0; rt < 2; ++rt)
    #pragma unroll
    for (int rg = 0; rg < 16; ++rg) {
      float rb = acc2[rt][rg] + acc2l[rt][rg] * WLINV;
      float p = acc[rt][rg] * rb * h0;
      p += __shfl_xor(p, 1); p += __shfl_xor(p, 2);
      p += __shfl_xor(p, 4); p += __shfl_xor(p, 8);
      p += __shfl_xor(p, 16);
      if (l31 == 0)
        part[wave][rt * 32 + 4 * l5 + (rg & 3) + 8 * (rg >> 2)] = p;
    }
  __syncthreads();
  if (t < TR) {
    long g = r0g + t;
    float pr = part[0][t] + part[1][t] + part[2][t] + part[3][t];
    float pm = pr * mask[g];
    if (br == 0) {
      atomicAdd(out + (int)(g & 127), pm * (1.0f / 3600.0f));
    } else {
      int b = (int)(g & 127);
      int j = (int)((g >> 7) & 63);
      float s = pm * (1.0f / 60.0f);
      float* fo = out + B_DIM + (j * B_DIM + b) * 3;
      atomicAdd(fo + 0, s * vh[g * 3 + 0]);
      atomicAdd(fo + 1, s * vh[g * 3 + 1]);
      atomicAdd(fo + 2, s * vh[g * 3 + 2]);
    }
  }
}

extern "C" void kernel_launch(void* const* d_in, const int* in_sizes, int n_in,
                              void* d_out, int out_size, void* d_ws, size_t ws_size,
                              hipStream_t stream) {
  const float* T    = (const float*)d_in[0];
  const float* mask = (const float*)d_in[1];
  const float* dist = (const float*)d_in[2];
  const float* vh   = (const float*)d_in[3];
  const float* eWin = (const float*)d_in[4];
  const float* ebin = (const float*)d_in[5];
  const float* eWh  = (const float*)d_in[6];
  const float* ebh  = (const float*)d_in[7];
  const float* eWout= (const float*)d_in[8];
  const float* ebout= (const float*)d_in[9];
  const float* erbf = (const float*)d_in[10];
  const float* ehead= (const float*)d_in[11];
  const float* fWin = (const float*)d_in[12];
  const float* fbin = (const float*)d_in[13];
  const float* fWh  = (const float*)d_in[14];
  const float* fbh  = (const float*)d_in[15];
  const float* fWout= (const float*)d_in[16];
  const float* fbout= (const float*)d_in[17];
  const float* frbf = (const float*)d_in[18];
  const float* fhead= (const float*)d_in[19];

  short* S = (short*)d_ws;                 // 576 KB of workspace
  float* out = (float*)d_out;

  zero_out<<<(NOUT + 255) / 256, 256, 0, stream>>>(out);
  prep_weights<<<576, 256, 0, stream>>>(eWin, eWh, eWout, erbf,
                                        fWin, fWh, fWout, frbf, S);
  fused_main<<<2 * (NROW / TR), 256, 0, stream>>>(
      T, mask, dist, vh,
      ebin, ebh, ebout, ehead,
      fbin, fbh, fbout, fhead,
      S, out);
}

// Round 3
// 811.082 us; speedup vs baseline: 1.6103x; 1.6103x over previous
//
#include <hip/hip_runtime.h>

#define A_DIM 64
#define B_DIM 128
#define E 128
#define NG 50
#define NROW (A_DIM*A_DIM*B_DIM)   // 524288
#define TR 64                      // rows per block
#define KS 136                     // xa row stride (shorts): 16B-aligned rows
#define SMS 72                     // smb row stride (shorts)
#define WBLK 512                   // shorts per (grp,plane,ksub) W fragment block (1 KB)
#define BR_STRIDE 147456           // shorts per branch: 18 chunks x 16 blocks x 512
#define NOUT (B_DIM + A_DIM*B_DIM*3)   // 24704 output floats
#define WLSCALE 64.0f              // W-lo pre-scale (avoids fp16 subnormal flush)
#define WLINV   0.015625f          // 1/64

using half8   = _Float16 __attribute__((ext_vector_type(8)));
using short8v = short __attribute__((ext_vector_type(8)));
using f32x16  = float __attribute__((ext_vector_type(16)));

__device__ __forceinline__ float silu_f(float x) {
  return x * __builtin_amdgcn_rcpf(1.0f + __expf(-x));
}
__device__ __forceinline__ short hbits(_Float16 h) {
  return (short)__builtin_bit_cast(unsigned short, h);
}

// One K=32 chunk, 2-term fp16: acc += xh*Wh ; accl += xh*(Wl*64).
// A (64 rows, single fp16 plane) from LDS; B from lane-ordered global fragment
// blocks (wl includes branch base + wave col-group + lane*8).
__device__ __forceinline__ void gemm_chunk32(
    const short* __restrict__ xh_, int xstr, int kcol,
    const short* __restrict__ wl_, int cidx,
    f32x16 acc[2], f32x16 accl[2], int l31, int l5)
{
  half8 bh[2], bl[2];
  #pragma unroll
  for (int s = 0; s < 2; ++s) {
    bh[s] = __builtin_bit_cast(half8,
              *(const short8v*)(wl_ + (size_t)(cidx * 16 + s) * WBLK));
    bl[s] = __builtin_bit_cast(half8,
              *(const short8v*)(wl_ + (size_t)(cidx * 16 + 2 + s) * WBLK));
  }
  #pragma unroll
  for (int rt = 0; rt < 2; ++rt) {
    const short* arow = xh_ + (rt * 32 + l31) * xstr + kcol + l5 * 8;
    #pragma unroll
    for (int s = 0; s < 2; ++s) {
      half8 a = __builtin_bit_cast(half8, *(const short8v*)(arow + s * 16));
      acc[rt]  = __builtin_amdgcn_mfma_f32_32x32x16_f16(a, bh[s], acc[rt],  0, 0, 0);
      accl[rt] = __builtin_amdgcn_mfma_f32_32x32x16_f16(a, bl[s], accl[rt], 0, 0, 0);
    }
  }
}

// Transpose + fp16 hi / scaled-lo split of all weights into lane-ordered
// fragment blocks. Fast axis is n -> coalesced W[k*128+n] loads.
// blk = cidx*16 + (n>>5)*4 + p*2 + (kk>>4); lane = (n&31)+32*((kk>>3)&1); e = kk&7.
// Blocks >= 576 zero the output buffer instead (fused zero_out).
__global__ __launch_bounds__(256) void prep_weights(
    const float* __restrict__ eWin, const float* __restrict__ eWh,
    const float* __restrict__ eWout, const float* __restrict__ erbf,
    const float* __restrict__ fWin, const float* __restrict__ fWh,
    const float* __restrict__ fWout, const float* __restrict__ frbf,
    short* __restrict__ S, float* __restrict__ out)
{
  if (blockIdx.x >= 576) {
    int i = (blockIdx.x - 576) * 256 + threadIdx.x;
    if (i < NOUT) out[i] = 0.0f;
    return;
  }
  int o = blockIdx.x * 256 + threadIdx.x;
  int br = (o >= 73728) ? 1 : 0;
  int r = o - br * 73728;
  short* base = S + br * BR_STRIDE;
  float v; int cidx, n, kk;
  if (r < 65536) {
    int lay = r >> 14, idx = r & 16383;
    int k = idx >> 7; n = idx & 127;
    const float* W = (lay == 0) ? (br ? fWin : eWin)
                   : (lay == 3) ? (br ? fWout : eWout)
                   : ((br ? fWh : eWh) + (lay - 1) * 16384);
    v = W[k * 128 + n];
    cidx = lay * 4 + (k >> 5); kk = k & 31;
  } else {
    int rr = r - 65536;                 // 0..8191
    int k = rr >> 7; n = rr & 127;
    v = (k < NG) ? (br ? frbf : erbf)[k * 128 + n] : 0.0f;
    cidx = 16 + (k >> 5); kk = k & 31;
  }
  int blk = cidx * 16 + (n >> 5) * 4 + (kk >> 4);                    // p = 0
  int idx2 = blk * WBLK + ((n & 31) + 32 * ((kk >> 3) & 1)) * 8 + (kk & 7);
  _Float16 wh = (_Float16)v;
  _Float16 wl = (_Float16)((v - (float)wh) * WLSCALE);
  base[idx2] = hbits(wh);
  base[idx2 + 2 * WBLK] = hbits(wl);                                 // p = 1
}

__global__ __launch_bounds__(256, 3) void fused_main(
    const float* __restrict__ T, const float* __restrict__ mask,
    const float* __restrict__ dist, const float* __restrict__ vh,
    const float* __restrict__ ebin, const float* __restrict__ ebh,
    const float* __restrict__ ebout, const float* __restrict__ ehead,
    const float* __restrict__ fbin, const float* __restrict__ fbh,
    const float* __restrict__ fbout, const float* __restrict__ fhead,
    const short* __restrict__ S,
    float* __restrict__ out)
{
  __shared__ short xa[TR * KS];       // single fp16 plane: 17408 B
  __shared__ float part[4][TR];       // 1024 B -> 18432 B total

  const int t = threadIdx.x;
  const int wave = t >> 6, lane = t & 63;
  const int l31 = lane & 31, l5 = lane >> 5;
  const int br = blockIdx.x & 1;
  const long tile = blockIdx.x >> 1;
  const long r0g = tile * TR;

  const short* wl = S + br * BR_STRIDE + wave * (4 * WBLK) + lane * 8;
  const float* bin  = br ? fbin : ebin;
  const float* bh_  = br ? fbh : ebh;
  const float* bout = br ? fbout : ebout;
  const float* head = br ? fhead : ehead;

  // ---- T tile -> xa fp16 plane ----
  {
    int row = t >> 2, seg = t & 3;
    const float* Tp = T + (r0g + row) * E + seg * 32;
    short* ph = xa + row * KS + seg * 32;
    #pragma unroll
    for (int j = 0; j < 8; ++j) {
      float4 v = *(const float4*)(Tp + j * 4);
      short4 s4 = make_short4(hbits((_Float16)v.x), hbits((_Float16)v.y),
                              hbits((_Float16)v.z), hbits((_Float16)v.w));
      *(short4*)(ph + j * 4) = s4;
    }
  }

  f32x16 acc[2], accl[2];

  // ---- 4 dense layers; W fragments stream L2->VGPR ----
  #pragma unroll 1
  for (int lay = 0; lay < 4; ++lay) {
    const float* bg = (lay == 0) ? bin : (lay == 3) ? bout : (bh_ + (lay - 1) * E);
    float b0 = bg[wave * 32 + l31];
    #pragma unroll
    for (int i = 0; i < 16; ++i) {
      acc[0][i] = b0; acc[1][i] = b0;
      accl[0][i] = 0.f; accl[1][i] = 0.f;
    }
    __syncthreads();                   // xa writes (stage / prev epilogue) visible
    #pragma unroll
    for (int ch = 0; ch < 4; ++ch)
      gemm_chunk32(xa, KS, ch * 32, wl, lay * 4 + ch, acc, accl, l31, l5);
    __syncthreads();                   // all xa reads of this layer done
    if (lay < 3) {
      #pragma unroll
      for (int rt = 0; rt < 2; ++rt)
        #pragma unroll
        for (int rg = 0; rg < 16; ++rg) {
          float y = acc[rt][rg] + accl[rt][rg] * WLINV;
          float v = silu_f(y);
          int rowa = rt * 32 + 4 * l5 + (rg & 3) + 8 * (rg >> 2);
          int col = wave * 32 + l31;
          short* slot = xa + rowa * KS + col;
          if (lay > 0) v += (float)*(const _Float16*)slot;  // residual (own slot)
          *slot = hbits((_Float16)v);
        }
    }
  }
  // fold feat: acc = Wout output (bias included, no activation)
  #pragma unroll
  for (int rt = 0; rt < 2; ++rt)
    #pragma unroll
    for (int i = 0; i < 16; ++i) acc[rt][i] += accl[rt][i] * WLINV;

  // ---- smeared gaussians -> sm fp16 plane (overlays xa; post-loop sync covers) ----
  short* smhi = xa;
  const float stepv = 12.0f / 49.0f;
  const float coeff = -0.5f / (stepv * stepv);
  {
    int r = t & 63, kg = t >> 6;
    float d = dist[r0g + r];
    #pragma unroll
    for (int j4 = 0; j4 < 4; ++j4) {
      float vv[4];
      #pragma unroll
      for (int jj = 0; jj < 4; ++jj) {
        int k = kg * 16 + j4 * 4 + jj;
        float dd = d - (float)k * stepv;
        vv[jj] = (k < NG) ? __expf(coeff * dd * dd) : 0.0f;
      }
      short4 s4 = make_short4(hbits((_Float16)vv[0]), hbits((_Float16)vv[1]),
                              hbits((_Float16)vv[2]), hbits((_Float16)vv[3]));
      *(short4*)(smhi + r * SMS + kg * 16 + j4 * 4) = s4;
    }
  }
  float h0 = head[wave * 32 + l31];
  f32x16 acc2[2], acc2l[2];
  #pragma unroll
  for (int i = 0; i < 16; ++i) {
    acc2[0][i] = 0.f; acc2[1][i] = 0.f;
    acc2l[0][i] = 0.f; acc2l[1][i] = 0.f;
  }
  __syncthreads();                     // sm plane visible
  gemm_chunk32(smhi, SMS, 0,  wl, 16, acc2, acc2l, l31, l5);
  gemm_chunk32(smhi, SMS, 32, wl, 17, acc2, acc2l, l31, l5);

  // ---- head dot: reduce over 32 cols per wave, cross-wave via LDS ----
  #pragma unroll
  for (int rt = 0; rt < 2; ++rt)
    #pragma unroll
    for (int rg = 0; rg < 16; ++rg) {
      float rb = acc2[rt][rg] + acc2l[rt][rg] * WLINV;
      float p = acc[rt][rg] * rb * h0;
      p += __shfl_xor(p, 1); p += __shfl_xor(p, 2);
      p += __shfl_xor(p, 4); p += __shfl_xor(p, 8);
      p += __shfl_xor(p, 16);
      if (l31 == 0)
        part[wave][rt * 32 + 4 * l5 + (rg & 3) + 8 * (rg >> 2)] = p;
    }
  __syncthreads();
  if (t < TR) {
    long g = r0g + t;
    float pr = part[0][t] + part[1][t] + part[2][t] + part[3][t];
    float pm = pr * mask[g];
    if (br == 0) {
      atomicAdd(out + (int)(g & 127), pm * (1.0f / 3600.0f));
    } else {
      int b = (int)(g & 127);
      int j = (int)((g >> 7) & 63);
      float s = pm * (1.0f / 60.0f);
      float* fo = out + B_DIM + (j * B_DIM + b) * 3;
      atomicAdd(fo + 0, s * vh[g * 3 + 0]);
      atomicAdd(fo + 1, s * vh[g * 3 + 1]);
      atomicAdd(fo + 2, s * vh[g * 3 + 2]);
    }
  }
}

extern "C" void kernel_launch(void* const* d_in, const int* in_sizes, int n_in,
                              void* d_out, int out_size, void* d_ws, size_t ws_size,
                              hipStream_t stream) {
  const float* T    = (const float*)d_in[0];
  const float* mask = (const float*)d_in[1];
  const float* dist = (const float*)d_in[2];
  const float* vh   = (const float*)d_in[3];
  const float* eWin = (const float*)d_in[4];
  const float* ebin = (const float*)d_in[5];
  const float* eWh  = (const float*)d_in[6];
  const float* ebh  = (const float*)d_in[7];
  const float* eWout= (const float*)d_in[8];
  const float* ebout= (const float*)d_in[9];
  const float* erbf = (const float*)d_in[10];
  const float* ehead= (const float*)d_in[11];
  const float* fWin = (const float*)d_in[12];
  const float* fbin = (const float*)d_in[13];
  const float* fWh  = (const float*)d_in[14];
  const float* fbh  = (const float*)d_in[15];
  const float* fWout= (const float*)d_in[16];
  const float* fbout= (const float*)d_in[17];
  const float* frbf = (const float*)d_in[18];
  const float* fhead= (const float*)d_in[19];

  short* S = (short*)d_ws;                 // 576 KB of workspace
  float* out = (float*)d_out;

  // 576 prep blocks + 97 zero blocks (fused)
  prep_weights<<<576 + (NOUT + 255) / 256, 256, 0, stream>>>(
      eWin, eWh, eWout, erbf, fWin, fWh, fWout, frbf, S, out);
  fused_main<<<2 * (NROW / TR), 256, 0, stream>>>(
      T, mask, dist, vh,
      ebin, ebh, ebout, ehead,
      fbin, fbh, fbout, fhead,
      S, out);
}